// Round 1
// baseline (42.535 us; speedup 1.0000x reference)
//
#include <hip/hip_runtime.h>
#include <hip/hip_bf16.h>

typedef __bf16 bf16x4 __attribute__((ext_vector_type(4)));
typedef __bf16 bf16x8 __attribute__((ext_vector_type(8)));
typedef float  f32x16 __attribute__((ext_vector_type(16)));

#define NROWS      27       // 1 dense + 26 sparse
#define D_DIM      128
#define OUT_COLS   479      // 128 dense + 351 upper-tri
#define ROW_BYTES  256      // 128 bf16 * 2B
#define SAMPLE_LDS (32 * ROW_BYTES)  // padded to 32 rows -> 8 KB per sample

// XOR swizzle within a 256B row: spreads the 16B slots of each row so that
// 32 lanes reading the same k-slot of rows 0..31 hit 16 distinct slots
// (2 lanes/bank = free). Same formula on write and read.
__device__ __forceinline__ int swz(int row, int byte_in_row) {
    return row * ROW_BYTES + (byte_in_row ^ ((row & 15) << 4));
}

__global__ __launch_bounds__(256)
void dlrm_interact_kernel(const float* __restrict__ dense,
                          const float* __restrict__ sparse,
                          float* __restrict__ out)
{
    __shared__ char lds[4 * SAMPLE_LDS];
    const int lane = threadIdx.x & 63;
    const int wid  = threadIdx.x >> 6;
    const int s    = blockIdx.x * 4 + wid;   // one sample per wave
    char* base = lds + wid * SAMPLE_LDS;

    // ---- dense row: fp32 passthrough to out + bf16 into LDS row 0 ----
    float d0 = dense[s * D_DIM + lane];
    float d1 = dense[s * D_DIM + 64 + lane];
    out[(size_t)s * OUT_COLS + lane]      = d0;
    out[(size_t)s * OUT_COLS + 64 + lane] = d1;
    // row 0: (row & 15) == 0 -> swizzle is identity, 2B writes are safe
    *(__bf16*)(base + swz(0, lane * 2))        = (__bf16)d0;
    *(__bf16*)(base + swz(0, (64 + lane) * 2)) = (__bf16)d1;

    // ---- sparse rows 1..26: 26*128 = 3328 fp32 = 832 float4 = 13 iters ----
    const float4* sp = (const float4*)(sparse + (size_t)s * 26 * D_DIM);
    #pragma unroll
    for (int it = 0; it < 13; ++it) {
        int f = it * 64 + lane;              // float4 index 0..831
        float4 v = sp[f];
        int row         = 1 + (f >> 5);      // 32 float4 per 128-wide row
        int byte_in_row = (f & 31) * 8;      // 4 bf16 = 8 bytes
        bf16x4 b;
        b[0] = (__bf16)v.x; b[1] = (__bf16)v.y;
        b[2] = (__bf16)v.z; b[3] = (__bf16)v.w;
        *(bf16x4*)(base + swz(row, byte_in_row)) = b;
    }

    // ---- zero-pad rows 27..31 (swizzle irrelevant for zeros) ----
    #pragma unroll
    for (int r = NROWS; r < 32; ++r) {
        *(int*)(base + r * ROW_BYTES + lane * 4) = 0;
    }

    __syncthreads();

    // ---- Gram = X * X^T via mfma_32x32x16_bf16, A-frag == B-frag ----
    f32x16 acc = {};
    const int row = lane & 31;
    const int ko  = (lane >> 5) * 16;        // which 8-bf16 half of the K=16 step
    #pragma unroll
    for (int st = 0; st < 8; ++st) {
        bf16x8 frag = *(bf16x8*)(base + swz(row, st * 32 + ko));
        acc = __builtin_amdgcn_mfma_f32_32x32x16_bf16(frag, frag, acc, 0, 0, 0);
    }

    // ---- scatter upper triangle (i<j, j<27) ----
    // C/D layout (m74/m101): col = lane&31, row = (q&3) + 8*(q>>2) + 4*(lane>>5)
    float* o = out + (size_t)s * OUT_COLS;
    const int j = lane & 31;
    #pragma unroll
    for (int q = 0; q < 16; ++q) {
        int i = (q & 3) + 8 * (q >> 2) + 4 * (lane >> 5);
        if (i < j && j < NROWS) {
            int idx = 128 + i * 26 - (i * (i - 1)) / 2 + (j - i - 1);
            o[idx] = acc[q];
        }
    }
}

extern "C" void kernel_launch(void* const* d_in, const int* in_sizes, int n_in,
                              void* d_out, int out_size, void* d_ws, size_t ws_size,
                              hipStream_t stream) {
    const float* dense  = (const float*)d_in[0];
    const float* sparse = (const float*)d_in[1];
    float* out = (float*)d_out;
    const int B = in_sizes[0] / D_DIM;       // 16384
    dim3 grid(B / 4), block(256);
    hipLaunchKernelGGL(dlrm_interact_kernel, grid, block, 0, stream,
                       dense, sparse, out);
}